// Round 14
// baseline (1054.536 us; speedup 1.0000x reference)
//
#include <hip/hip_runtime.h>
#include <cstdint>
#include <math.h>

#define NB 4
#define NN 512
#define DH 128
#define NHEADS 8
#define NHID 16
#define ITILE 64
#define SENTINEL -1e30f

// ---- packed-f32 helpers (VOP3P, verified R9) ----
typedef __attribute__((ext_vector_type(2))) float f32x2;
__device__ __forceinline__ f32x2 pk_fma_blo(f32x2 a, f32x2 b, f32x2 c) {
    f32x2 d;
    asm("v_pk_fma_f32 %0, %1, %2, %3 op_sel_hi:[1,0,1]"
        : "=v"(d) : "v"(a), "v"(b), "v"(c));
    return d;
}
__device__ __forceinline__ f32x2 pk_fma_bhi(f32x2 a, f32x2 b, f32x2 c) {
    f32x2 d;
    asm("v_pk_fma_f32 %0, %1, %2, %3 op_sel:[0,1,0] op_sel_hi:[1,1,1]"
        : "=v"(d) : "v"(a), "v"(b), "v"(c));
    return d;
}
__device__ __forceinline__ f32x2 pk_add(f32x2 a, f32x2 b) {
    f32x2 d;
    asm("v_pk_add_f32 %0, %1, %2" : "=v"(d) : "v"(a), "v"(b));
    return d;
}
__device__ __forceinline__ f32x2 shfl_xor_f2(f32x2 v, int m) {
    double d = __builtin_bit_cast(double, v);
    d = __shfl_xor(d, m);
    return __builtin_bit_cast(f32x2, d);
}

// ---- fully-fused GAT layer v7b: R9 proj + WAVE-AUTONOMOUS attention ----
// 3 dispatches. Block (b, hh, it): 512 threads, 87.0 KB LDS, 1 block/CU.
// v7 (R13) FAILED on an LDS layout bug: Sgr was placed at smem+8448, inside
// Sgl's [4352,12544) range (each f-major plane is 8192 floats, not 4096) ->
// gl chunks 2,3 clobbered. This round fixes ONLY the layout:
//   s_W[0,4096) s_Win[4096,4352) Sgl[4352,12544) Sgr[12544,20736)
//   s_dgl[20736,21248) s_dgr[21248,21760)  = 87,040 B.
// Structure unchanged: each 8-lane group owns ONE row and scans all 512 j;
// two-pass register softmax (sc[64]); 3x shfl_xor row reduce; butterfly acc
// merge; direct store. No barriers after dgl -> waves drift and hide each
// other's stalls (R12 accounting: ~13us busy vs 40us measured, 7 barriers).
__global__ __launch_bounds__(512, 1) void gat_layer(
    const int lay,
    const float* __restrict__ X,
    const float* __restrict__ hTin, float* __restrict__ hTout,
    const float* __restrict__ Win,
    const float* __restrict__ WlL, const float* __restrict__ WrL,
    const float* __restrict__ a_vec, const float* __restrict__ Wout,
    float* __restrict__ out, uint32_t* __restrict__ adjb,
    const int* __restrict__ adj)
{
    __shared__ __align__(16) float smem[21760];   // 87,040 B -> 1 block/CU
    float* s_W   = smem;                  // [128][32] cols 0-15 Wl, 16-31 Wr
    float* s_Win = smem + 4096;           // [2][128] (layer 0 only)
    float4* Sgl  = (float4*)(smem + 4352);    // [4][512] f-major gl chunks
    float4* Sgr  = (float4*)(smem + 12544);   // [4][512] f-major gr chunks
    float* s_dgl = smem + 20736;          // [512]
    float* s_dgr = smem + 21248;          // [512]

    const int blk = blockIdx.x;           // 256 = ((b*8+hh)*8) + it
    const int it  = blk & 7;
    const int bh  = blk >> 3;
    const int b   = bh >> 3;
    const int hh  = bh & 7;
    const int i0  = it * ITILE;
    const int t   = threadIdx.x;
    const int il  = t & 31;
    const int js  = t >> 5;               // [0,16) -- used by adj pack only

    // ---- stage W head-slices -> s_W[k][32]; Win (layer 0) ----
    for (int c = t; c < 1024; c += 512) {
        const int k = c >> 3, j = c & 7;
        if (j < 4)
            *(float4*)&s_W[k * 32 + j * 4] =
                *(const float4*)&WlL[k * DH + hh * NHID + j * 4];
        else
            *(float4*)&s_W[k * 32 + 16 + (j - 4) * 4] =
                *(const float4*)&WrL[k * DH + hh * NHID + (j - 4) * 4];
    }
    if (lay == 0 && t < 64) ((float4*)s_Win)[t] = ((const float4*)Win)[t];

    float a[16];
#pragma unroll
    for (int q = 0; q < 4; ++q) {
        const float4 v = ((const float4*)a_vec)[q];
        a[4*q+0] = v.x; a[4*q+1] = v.y; a[4*q+2] = v.z; a[4*q+3] = v.w;
    }

    // ---- layer 0: pack adj bitmasks for layers 1-2 (writes only) ----
    if (lay == 0) {
        const int r0 = i0 + il, r1 = r0 + 32;
        const int4* p0 = (const int4*)(adj + ((size_t)(b * NN + r0)) * NN + js * 32);
        const int4* p1 = (const int4*)(adj + ((size_t)(b * NN + r1)) * NN + js * 32);
        uint32_t m0 = 0, m1 = 0;
#pragma unroll
        for (int c = 0; c < 8; ++c) {
            const int4 v0 = p0[c], v1 = p1[c];
            m0 |= (v0.x != 0 ? 1u : 0u) << (c * 4 + 0);
            m0 |= (v0.y != 0 ? 1u : 0u) << (c * 4 + 1);
            m0 |= (v0.z != 0 ? 1u : 0u) << (c * 4 + 2);
            m0 |= (v0.w != 0 ? 1u : 0u) << (c * 4 + 3);
            m1 |= (v1.x != 0 ? 1u : 0u) << (c * 4 + 0);
            m1 |= (v1.y != 0 ? 1u : 0u) << (c * 4 + 1);
            m1 |= (v1.z != 0 ? 1u : 0u) << (c * 4 + 2);
            m1 |= (v1.w != 0 ? 1u : 0u) << (c * 4 + 3);
        }
        adjb[((size_t)(b * NN + r0)) * 16 + js] = m0;  // 8 hh-blocks same value: benign
        adjb[((size_t)(b * NN + r1)) * 16 + js] = m1;
    }
    __syncthreads();                      // s_W/s_Win staged

    // ---- proj (R9-verified): thread (c4, rq) -> rows 4rq..4rq+3, cols c4*8..+7 ----
    {
        const int c4 = t >> 7;            // wave-uniform (2 waves per c4)
        const int rq = t & 127;
        const float* wcol = s_W + ((c4 >> 1) * 16 + (c4 & 1) * 8);
        f32x2 acc2[4][4];                 // [row][colpair]
#pragma unroll
        for (int m = 0; m < 4; ++m)
#pragma unroll
            for (int c = 0; c < 4; ++c) acc2[m][c] = (f32x2){0.f, 0.f};

        if (lay == 0) {
            const float4 xa = *(const float4*)&X[(size_t)(b * NN + 4 * rq) * 2];
            const float4 xb = *(const float4*)&X[(size_t)(b * NN + 4 * rq) * 2 + 4];
            const float x0[4] = {xa.x, xa.z, xb.x, xb.z};
            const float x1[4] = {xa.y, xa.w, xb.y, xb.w};
#pragma unroll 2
            for (int kq = 0; kq < 32; ++kq) {
                const float4 w0 = *(const float4*)&s_Win[kq * 4];
                const float4 w1 = *(const float4*)&s_Win[128 + kq * 4];
                const float w0a[4] = {w0.x, w0.y, w0.z, w0.w};
                const float w1a[4] = {w1.x, w1.y, w1.z, w1.w};
#pragma unroll
                for (int kk = 0; kk < 4; ++kk) {
                    const int k = kq * 4 + kk;
                    const float4 wa = *(const float4*)&wcol[k * 32];
                    const float4 wb = *(const float4*)&wcol[k * 32 + 4];
                    const f32x2 W0 = {wa.x, wa.y}, W1 = {wa.z, wa.w};
                    const f32x2 W2 = {wb.x, wb.y}, W3 = {wb.z, wb.w};
                    const float hm0 = x0[0] * w0a[kk] + x1[0] * w1a[kk];
                    const float hm1 = x0[1] * w0a[kk] + x1[1] * w1a[kk];
                    const float hm2 = x0[2] * w0a[kk] + x1[2] * w1a[kk];
                    const float hm3 = x0[3] * w0a[kk] + x1[3] * w1a[kk];
                    const f32x2 H0 = {hm0, hm1}, H1 = {hm2, hm3};
                    acc2[0][0] = pk_fma_blo(W0, H0, acc2[0][0]);
                    acc2[0][1] = pk_fma_blo(W1, H0, acc2[0][1]);
                    acc2[0][2] = pk_fma_blo(W2, H0, acc2[0][2]);
                    acc2[0][3] = pk_fma_blo(W3, H0, acc2[0][3]);
                    acc2[1][0] = pk_fma_bhi(W0, H0, acc2[1][0]);
                    acc2[1][1] = pk_fma_bhi(W1, H0, acc2[1][1]);
                    acc2[1][2] = pk_fma_bhi(W2, H0, acc2[1][2]);
                    acc2[1][3] = pk_fma_bhi(W3, H0, acc2[1][3]);
                    acc2[2][0] = pk_fma_blo(W0, H1, acc2[2][0]);
                    acc2[2][1] = pk_fma_blo(W1, H1, acc2[2][1]);
                    acc2[2][2] = pk_fma_blo(W2, H1, acc2[2][2]);
                    acc2[2][3] = pk_fma_blo(W3, H1, acc2[2][3]);
                    acc2[3][0] = pk_fma_bhi(W0, H1, acc2[3][0]);
                    acc2[3][1] = pk_fma_bhi(W1, H1, acc2[3][1]);
                    acc2[3][2] = pk_fma_bhi(W2, H1, acc2[3][2]);
                    acc2[3][3] = pk_fma_bhi(W3, H1, acc2[3][3]);
                }
            }
        } else {
            const float* hT = hTin + (size_t)b * DH * NN + 4 * rq;   // [128][512]
#pragma unroll 1
            for (int kb = 0; kb < DH; kb += 16) {
                float4 hb[16];            // 16 independent loads in flight
#pragma unroll
                for (int u = 0; u < 16; ++u)
                    hb[u] = *(const float4*)&hT[(size_t)(kb + u) * NN];
#pragma unroll
                for (int u = 0; u < 16; ++u) {
                    const int k = kb + u;
                    const float4 wa = *(const float4*)&wcol[k * 32];  // broadcast
                    const float4 wb = *(const float4*)&wcol[k * 32 + 4];
                    const f32x2 W0 = {wa.x, wa.y}, W1 = {wa.z, wa.w};
                    const f32x2 W2 = {wb.x, wb.y}, W3 = {wb.z, wb.w};
                    const f32x2 H0 = {hb[u].x, hb[u].y}, H1 = {hb[u].z, hb[u].w};
                    acc2[0][0] = pk_fma_blo(W0, H0, acc2[0][0]);
                    acc2[0][1] = pk_fma_blo(W1, H0, acc2[0][1]);
                    acc2[0][2] = pk_fma_blo(W2, H0, acc2[0][2]);
                    acc2[0][3] = pk_fma_blo(W3, H0, acc2[0][3]);
                    acc2[1][0] = pk_fma_bhi(W0, H0, acc2[1][0]);
                    acc2[1][1] = pk_fma_bhi(W1, H0, acc2[1][1]);
                    acc2[1][2] = pk_fma_bhi(W2, H0, acc2[1][2]);
                    acc2[1][3] = pk_fma_bhi(W3, H0, acc2[1][3]);
                    acc2[2][0] = pk_fma_blo(W0, H1, acc2[2][0]);
                    acc2[2][1] = pk_fma_blo(W1, H1, acc2[2][1]);
                    acc2[2][2] = pk_fma_blo(W2, H1, acc2[2][2]);
                    acc2[2][3] = pk_fma_blo(W3, H1, acc2[2][3]);
                    acc2[3][0] = pk_fma_bhi(W0, H1, acc2[3][0]);
                    acc2[3][1] = pk_fma_bhi(W1, H1, acc2[3][1]);
                    acc2[3][2] = pk_fma_bhi(W2, H1, acc2[3][2]);
                    acc2[3][3] = pk_fma_bhi(W3, H1, acc2[3][3]);
                }
            }
        }
        // write f-major plane slices
        float4* Sg = (c4 < 2) ? Sgl : Sgr;
        const int q0 = (c4 & 1) * 2;
#pragma unroll
        for (int m = 0; m < 4; ++m) {
            float4 v0, v1;
            v0.x = acc2[m][0].x; v0.y = acc2[m][0].y;
            v0.z = acc2[m][1].x; v0.w = acc2[m][1].y;
            v1.x = acc2[m][2].x; v1.y = acc2[m][2].y;
            v1.z = acc2[m][3].x; v1.w = acc2[m][3].y;
            Sg[q0 * 512       + 4 * rq + m] = v0;
            Sg[(q0 + 1) * 512 + 4 * rq + m] = v1;
        }
    }
    __syncthreads();                      // planes complete

    {   // dgl[t] = a . gl[t], dgr[t] = a . gr[t] (lane-consecutive reads)
        float dl = 0.f, dr = 0.f;
#pragma unroll
        for (int q = 0; q < 4; ++q) {
            const float4 vl = Sgl[q * 512 + t];
            const float4 vr = Sgr[q * 512 + t];
            dl = fmaf(a[4*q+0], vl.x, dl); dl = fmaf(a[4*q+1], vl.y, dl);
            dl = fmaf(a[4*q+2], vl.z, dl); dl = fmaf(a[4*q+3], vl.w, dl);
            dr = fmaf(a[4*q+0], vr.x, dr); dr = fmaf(a[4*q+1], vr.y, dr);
            dr = fmaf(a[4*q+2], vr.z, dr); dr = fmaf(a[4*q+3], vr.w, dr);
        }
        s_dgl[t] = dl;
        s_dgr[t] = dr;
    }
    __syncthreads();                      // dgl/dgr ready -- LAST barrier

    // ================= wave-autonomous attention =================
    const int lane = t & 63;
    const int g    = lane >> 3;           // row group within wave
    const int lg   = lane & 7;            // lane within group
    const int row  = i0 + (t >> 6) * 8 + g;

    // row's gr fragment (8 lanes same row -> broadcast reads)
    f32x2 grip[8];
#pragma unroll
    for (int q = 0; q < 4; ++q) {
        const float4 v = Sgr[q * 512 + row];
        grip[2*q+0] = (f32x2){v.x, v.y};
        grip[2*q+1] = (f32x2){v.z, v.w};
    }
    const float cc = 0.6f * s_dgr[row];

    // ---- pass 1: 64 scores (j = w*32 + u*8 + lg), running lane max ----
    float sc[64];
    float mx = SENTINEL;
#pragma unroll
    for (int w = 0; w < 16; ++w) {
        uint32_t mbits;
        if (lay == 0) {
            const int* arow = adj + ((size_t)(b * NN + row)) * NN + w * 32 + lg;
            mbits  = (arow[0]  != 0 ? 1u : 0u);
            mbits |= (arow[8]  != 0 ? 2u : 0u);
            mbits |= (arow[16] != 0 ? 4u : 0u);
            mbits |= (arow[24] != 0 ? 8u : 0u);
        } else {
            const uint32_t word = adjb[((size_t)(b * NN + row)) * 16 + w];
            mbits = ((word >> lg) & 1u)
                  | (((word >> ( 8 + lg)) & 1u) << 1)
                  | (((word >> (16 + lg)) & 1u) << 2)
                  | (((word >> (24 + lg)) & 1u) << 3);
        }
#pragma unroll
        for (int u = 0; u < 4; ++u) {
            const int j = w * 32 + u * 8 + lg;
            const float dj = s_dgl[j];
            float s = 0.f;
#pragma unroll
            for (int q = 0; q < 4; ++q) {
                const float4 gv = Sgl[q * 512 + j];   // 8 consecutive addrs/wave
                const f32x2 Ga = {gv.x, gv.y}, Gb = {gv.z, gv.w};
                const f32x2 va = pk_add(Ga, grip[2*q+0]);
                const f32x2 vb = pk_add(Gb, grip[2*q+1]);
                s = fmaf(a[4*q+0], fabsf(va.x), s);
                s = fmaf(a[4*q+1], fabsf(va.y), s);
                s = fmaf(a[4*q+2], fabsf(vb.x), s);
                s = fmaf(a[4*q+3], fabsf(vb.y), s);
            }
            const float bb = fmaf(0.6f, dj, cc);
            const float v  = ((mbits >> u) & 1u) ? fmaf(0.4f, s, bb) : SENTINEL;
            sc[w * 4 + u] = v;
            mx = fmaxf(mx, v);
        }
    }
    // group (= full row) max via butterfly
    mx = fmaxf(mx, __shfl_xor(mx, 1));
    mx = fmaxf(mx, __shfl_xor(mx, 2));
    mx = fmaxf(mx, __shfl_xor(mx, 4));

    // exp + row denom
    float L = 0.f;
#pragma unroll
    for (int n = 0; n < 64; ++n) { sc[n] = __expf(sc[n] - mx); L += sc[n]; }
    L += __shfl_xor(L, 1);
    L += __shfl_xor(L, 2);
    L += __shfl_xor(L, 4);
    const float inv = 1.f / L;

    // ---- pass 2: PV accumulate (unnormalized) ----
    f32x2 accp[8];
#pragma unroll
    for (int p2 = 0; p2 < 8; ++p2) accp[p2] = (f32x2){0.f, 0.f};
#pragma unroll
    for (int w = 0; w < 16; ++w) {
#pragma unroll
        for (int u = 0; u < 4; ++u) {
            const int j = w * 32 + u * 8 + lg;
            const float p = sc[w * 4 + u];
            const f32x2 pp = {p, p};
#pragma unroll
            for (int q = 0; q < 4; ++q) {
                const float4 gv = Sgr[q * 512 + j];
                const f32x2 Ga = {gv.x, gv.y}, Gb = {gv.z, gv.w};
                accp[2*q+0] = pk_fma_blo(Ga, pp, accp[2*q+0]);
                accp[2*q+1] = pk_fma_blo(Gb, pp, accp[2*q+1]);
            }
        }
    }
    // butterfly acc merge within group (all 8 lanes end with full row acc)
#pragma unroll
    for (int p2 = 0; p2 < 8; ++p2) accp[p2] = pk_add(accp[p2], shfl_xor_f2(accp[p2], 1));
#pragma unroll
    for (int p2 = 0; p2 < 8; ++p2) accp[p2] = pk_add(accp[p2], shfl_xor_f2(accp[p2], 2));
#pragma unroll
    for (int p2 = 0; p2 < 8; ++p2) accp[p2] = pk_add(accp[p2], shfl_xor_f2(accp[p2], 4));

    // ---- normalize + write (lane lg owns f = 2lg, 2lg+1) ----
    const f32x2 acc_o = accp[lg] * (f32x2){inv, inv};
    if (Wout) {                           // fused h @ W_out per head
        const float w0 = Wout[hh * NHID + 2 * lg];
        const float w1 = Wout[hh * NHID + 2 * lg + 1];
        float v = acc_o.x * w0 + acc_o.y * w1;
        v += __shfl_xor(v, 1);
        v += __shfl_xor(v, 2);
        v += __shfl_xor(v, 4);
        if (lg == 0) atomicAdd(out + b * NN + row, v);
    } else {                              // transposed activation for next layer
        float* dst = hTout + ((size_t)b * DH + hh * NHID + 2 * lg) * NN + row;
        dst[0]  = acc_o.x;
        dst[NN] = acc_o.y;
    }

    // layer 1 zeroes the atomic target for layer 2 (stream-ordered)
    if (lay == 1 && blk < 4) out[blk * 512 + t] = 0.f;
}

extern "C" void kernel_launch(void* const* d_in, const int* in_sizes, int n_in,
                              void* d_out, int out_size, void* d_ws, size_t ws_size,
                              hipStream_t stream) {
    const float* X    = (const float*)d_in[0];   // [4,512,2]
    const int*   adj  = (const int*)  d_in[1];   // [4,512,512]
    const float* Win  = (const float*)d_in[2];   // [2,128]
    const float* Wl   = (const float*)d_in[3];   // [3,128,128]
    const float* Wr   = (const float*)d_in[4];   // [3,128,128]
    const float* Aa   = (const float*)d_in[5];   // [3,16]
    const float* Wout = (const float*)d_in[6];   // [128,1]
    float* out = (float*)d_out;                  // [4,512] fp32

    float*    ws   = (float*)d_ws;
    float*    hT_a = ws;                         // 1 MB, [4][128][512]
    float*    hT_b = ws + 262144;                // 1 MB
    uint32_t* adjb = (uint32_t*)(ws + 524288);   // 128 KB

    gat_layer<<<256, 512, 0, stream>>>(0, X, nullptr, hT_a, Win,
        Wl,               Wr,               Aa,      nullptr, out, adjb, adj);
    gat_layer<<<256, 512, 0, stream>>>(1, nullptr, hT_a, hT_b, Win,
        Wl + DH * DH,     Wr + DH * DH,     Aa + 16, nullptr, out, adjb, adj);
    gat_layer<<<256, 512, 0, stream>>>(2, nullptr, hT_b, nullptr, Win,
        Wl + 2 * DH * DH, Wr + 2 * DH * DH, Aa + 32, Wout,    out, adjb, adj);
}

// Round 15
// 171.024 us; speedup vs baseline: 6.1660x; 6.1660x over previous
//
#include <hip/hip_runtime.h>
#include <cstdint>
#include <math.h>

#define NB 4
#define NN 512
#define DH 128
#define NHEADS 8
#define NHID 16
#define ITILE 64
#define SENTINEL -1e30f

// ---- packed-f32 helpers (VOP3P, verified R9) ----
typedef __attribute__((ext_vector_type(2))) float f32x2;
__device__ __forceinline__ f32x2 pk_fma_blo(f32x2 a, f32x2 b, f32x2 c) {
    f32x2 d;
    asm("v_pk_fma_f32 %0, %1, %2, %3 op_sel_hi:[1,0,1]"
        : "=v"(d) : "v"(a), "v"(b), "v"(c));
    return d;
}
__device__ __forceinline__ f32x2 pk_fma_bhi(f32x2 a, f32x2 b, f32x2 c) {
    f32x2 d;
    asm("v_pk_fma_f32 %0, %1, %2, %3 op_sel:[0,1,0] op_sel_hi:[1,1,1]"
        : "=v"(d) : "v"(a), "v"(b), "v"(c));
    return d;
}
__device__ __forceinline__ f32x2 pk_add(f32x2 a, f32x2 b) {
    f32x2 d;
    asm("v_pk_add_f32 %0, %1, %2" : "=v"(d) : "v"(a), "v"(b));
    return d;
}
__device__ __forceinline__ f32x2 shfl_xor_f2(f32x2 v, int m) {
    double d = __builtin_bit_cast(double, v);
    d = __shfl_xor(d, m);
    return __builtin_bit_cast(f32x2, d);
}

// ---- fully-fused GAT layer v7c: R9 proj + wave-autonomous attn, NO sc[] ----
// 3 dispatches. Block (b, hh, it): 512 threads, 87.0 KB LDS, 1 block/CU.
// R14 passed correctness but spilled: sc[64] pushed attn-phase demand past
// the 128-VGPR cap -> 429 MB scratch writes, 347 us/layer. This round keeps
// the exact structure but RECOMPUTES scores in pass 2 instead of storing
// them (bitwise-identical ops -> same values). Attn-phase registers drop to
// ~80 (mb[16] mask cache + grip 16 + accp 16 + a 16). Cost: score VALU x2
// (~+2 us/layer) vs the ~20 us/layer of barrier-drain the structure removes.
// Pass 1: row max only. Pass 2: recompute score, exp, denom + PV accumulate.
__global__ __launch_bounds__(512, 1) void gat_layer(
    const int lay,
    const float* __restrict__ X,
    const float* __restrict__ hTin, float* __restrict__ hTout,
    const float* __restrict__ Win,
    const float* __restrict__ WlL, const float* __restrict__ WrL,
    const float* __restrict__ a_vec, const float* __restrict__ Wout,
    float* __restrict__ out, uint32_t* __restrict__ adjb,
    const int* __restrict__ adj)
{
    __shared__ __align__(16) float smem[21760];   // 87,040 B -> 1 block/CU
    float* s_W   = smem;                  // [128][32] cols 0-15 Wl, 16-31 Wr
    float* s_Win = smem + 4096;           // [2][128] (layer 0 only)
    float4* Sgl  = (float4*)(smem + 4352);    // [4][512] f-major gl chunks
    float4* Sgr  = (float4*)(smem + 12544);   // [4][512] f-major gr chunks
    float* s_dgl = smem + 20736;          // [512]
    float* s_dgr = smem + 21248;          // [512]

    const int blk = blockIdx.x;           // 256 = ((b*8+hh)*8) + it
    const int it  = blk & 7;
    const int bh  = blk >> 3;
    const int b   = bh >> 3;
    const int hh  = bh & 7;
    const int i0  = it * ITILE;
    const int t   = threadIdx.x;
    const int il  = t & 31;
    const int js  = t >> 5;               // [0,16) -- used by adj pack only

    // ---- stage W head-slices -> s_W[k][32]; Win (layer 0) ----
    for (int c = t; c < 1024; c += 512) {
        const int k = c >> 3, j = c & 7;
        if (j < 4)
            *(float4*)&s_W[k * 32 + j * 4] =
                *(const float4*)&WlL[k * DH + hh * NHID + j * 4];
        else
            *(float4*)&s_W[k * 32 + 16 + (j - 4) * 4] =
                *(const float4*)&WrL[k * DH + hh * NHID + (j - 4) * 4];
    }
    if (lay == 0 && t < 64) ((float4*)s_Win)[t] = ((const float4*)Win)[t];

    float a[16];
#pragma unroll
    for (int q = 0; q < 4; ++q) {
        const float4 v = ((const float4*)a_vec)[q];
        a[4*q+0] = v.x; a[4*q+1] = v.y; a[4*q+2] = v.z; a[4*q+3] = v.w;
    }

    // ---- layer 0: pack adj bitmasks for layers 1-2 (writes only) ----
    if (lay == 0) {
        const int r0 = i0 + il, r1 = r0 + 32;
        const int4* p0 = (const int4*)(adj + ((size_t)(b * NN + r0)) * NN + js * 32);
        const int4* p1 = (const int4*)(adj + ((size_t)(b * NN + r1)) * NN + js * 32);
        uint32_t m0 = 0, m1 = 0;
#pragma unroll
        for (int c = 0; c < 8; ++c) {
            const int4 v0 = p0[c], v1 = p1[c];
            m0 |= (v0.x != 0 ? 1u : 0u) << (c * 4 + 0);
            m0 |= (v0.y != 0 ? 1u : 0u) << (c * 4 + 1);
            m0 |= (v0.z != 0 ? 1u : 0u) << (c * 4 + 2);
            m0 |= (v0.w != 0 ? 1u : 0u) << (c * 4 + 3);
            m1 |= (v1.x != 0 ? 1u : 0u) << (c * 4 + 0);
            m1 |= (v1.y != 0 ? 1u : 0u) << (c * 4 + 1);
            m1 |= (v1.z != 0 ? 1u : 0u) << (c * 4 + 2);
            m1 |= (v1.w != 0 ? 1u : 0u) << (c * 4 + 3);
        }
        adjb[((size_t)(b * NN + r0)) * 16 + js] = m0;  // 8 hh-blocks same value: benign
        adjb[((size_t)(b * NN + r1)) * 16 + js] = m1;
    }
    __syncthreads();                      // s_W/s_Win staged

    // ---- proj (R9-verified): thread (c4, rq) -> rows 4rq..4rq+3, cols c4*8..+7 ----
    {
        const int c4 = t >> 7;            // wave-uniform (2 waves per c4)
        const int rq = t & 127;
        const float* wcol = s_W + ((c4 >> 1) * 16 + (c4 & 1) * 8);
        f32x2 acc2[4][4];                 // [row][colpair]
#pragma unroll
        for (int m = 0; m < 4; ++m)
#pragma unroll
            for (int c = 0; c < 4; ++c) acc2[m][c] = (f32x2){0.f, 0.f};

        if (lay == 0) {
            const float4 xa = *(const float4*)&X[(size_t)(b * NN + 4 * rq) * 2];
            const float4 xb = *(const float4*)&X[(size_t)(b * NN + 4 * rq) * 2 + 4];
            const float x0[4] = {xa.x, xa.z, xb.x, xb.z};
            const float x1[4] = {xa.y, xa.w, xb.y, xb.w};
#pragma unroll 2
            for (int kq = 0; kq < 32; ++kq) {
                const float4 w0 = *(const float4*)&s_Win[kq * 4];
                const float4 w1 = *(const float4*)&s_Win[128 + kq * 4];
                const float w0a[4] = {w0.x, w0.y, w0.z, w0.w};
                const float w1a[4] = {w1.x, w1.y, w1.z, w1.w};
#pragma unroll
                for (int kk = 0; kk < 4; ++kk) {
                    const int k = kq * 4 + kk;
                    const float4 wa = *(const float4*)&wcol[k * 32];
                    const float4 wb = *(const float4*)&wcol[k * 32 + 4];
                    const f32x2 W0 = {wa.x, wa.y}, W1 = {wa.z, wa.w};
                    const f32x2 W2 = {wb.x, wb.y}, W3 = {wb.z, wb.w};
                    const float hm0 = x0[0] * w0a[kk] + x1[0] * w1a[kk];
                    const float hm1 = x0[1] * w0a[kk] + x1[1] * w1a[kk];
                    const float hm2 = x0[2] * w0a[kk] + x1[2] * w1a[kk];
                    const float hm3 = x0[3] * w0a[kk] + x1[3] * w1a[kk];
                    const f32x2 H0 = {hm0, hm1}, H1 = {hm2, hm3};
                    acc2[0][0] = pk_fma_blo(W0, H0, acc2[0][0]);
                    acc2[0][1] = pk_fma_blo(W1, H0, acc2[0][1]);
                    acc2[0][2] = pk_fma_blo(W2, H0, acc2[0][2]);
                    acc2[0][3] = pk_fma_blo(W3, H0, acc2[0][3]);
                    acc2[1][0] = pk_fma_bhi(W0, H0, acc2[1][0]);
                    acc2[1][1] = pk_fma_bhi(W1, H0, acc2[1][1]);
                    acc2[1][2] = pk_fma_bhi(W2, H0, acc2[1][2]);
                    acc2[1][3] = pk_fma_bhi(W3, H0, acc2[1][3]);
                    acc2[2][0] = pk_fma_blo(W0, H1, acc2[2][0]);
                    acc2[2][1] = pk_fma_blo(W1, H1, acc2[2][1]);
                    acc2[2][2] = pk_fma_blo(W2, H1, acc2[2][2]);
                    acc2[2][3] = pk_fma_blo(W3, H1, acc2[2][3]);
                    acc2[3][0] = pk_fma_bhi(W0, H1, acc2[3][0]);
                    acc2[3][1] = pk_fma_bhi(W1, H1, acc2[3][1]);
                    acc2[3][2] = pk_fma_bhi(W2, H1, acc2[3][2]);
                    acc2[3][3] = pk_fma_bhi(W3, H1, acc2[3][3]);
                }
            }
        } else {
            const float* hT = hTin + (size_t)b * DH * NN + 4 * rq;   // [128][512]
#pragma unroll 1
            for (int kb = 0; kb < DH; kb += 16) {
                float4 hb[16];            // 16 independent loads in flight
#pragma unroll
                for (int u = 0; u < 16; ++u)
                    hb[u] = *(const float4*)&hT[(size_t)(kb + u) * NN];
#pragma unroll
                for (int u = 0; u < 16; ++u) {
                    const int k = kb + u;
                    const float4 wa = *(const float4*)&wcol[k * 32];  // broadcast
                    const float4 wb = *(const float4*)&wcol[k * 32 + 4];
                    const f32x2 W0 = {wa.x, wa.y}, W1 = {wa.z, wa.w};
                    const f32x2 W2 = {wb.x, wb.y}, W3 = {wb.z, wb.w};
                    const f32x2 H0 = {hb[u].x, hb[u].y}, H1 = {hb[u].z, hb[u].w};
                    acc2[0][0] = pk_fma_blo(W0, H0, acc2[0][0]);
                    acc2[0][1] = pk_fma_blo(W1, H0, acc2[0][1]);
                    acc2[0][2] = pk_fma_blo(W2, H0, acc2[0][2]);
                    acc2[0][3] = pk_fma_blo(W3, H0, acc2[0][3]);
                    acc2[1][0] = pk_fma_bhi(W0, H0, acc2[1][0]);
                    acc2[1][1] = pk_fma_bhi(W1, H0, acc2[1][1]);
                    acc2[1][2] = pk_fma_bhi(W2, H0, acc2[1][2]);
                    acc2[1][3] = pk_fma_bhi(W3, H0, acc2[1][3]);
                    acc2[2][0] = pk_fma_blo(W0, H1, acc2[2][0]);
                    acc2[2][1] = pk_fma_blo(W1, H1, acc2[2][1]);
                    acc2[2][2] = pk_fma_blo(W2, H1, acc2[2][2]);
                    acc2[2][3] = pk_fma_blo(W3, H1, acc2[2][3]);
                    acc2[3][0] = pk_fma_bhi(W0, H1, acc2[3][0]);
                    acc2[3][1] = pk_fma_bhi(W1, H1, acc2[3][1]);
                    acc2[3][2] = pk_fma_bhi(W2, H1, acc2[3][2]);
                    acc2[3][3] = pk_fma_bhi(W3, H1, acc2[3][3]);
                }
            }
        }
        // write f-major plane slices
        float4* Sg = (c4 < 2) ? Sgl : Sgr;
        const int q0 = (c4 & 1) * 2;
#pragma unroll
        for (int m = 0; m < 4; ++m) {
            float4 v0, v1;
            v0.x = acc2[m][0].x; v0.y = acc2[m][0].y;
            v0.z = acc2[m][1].x; v0.w = acc2[m][1].y;
            v1.x = acc2[m][2].x; v1.y = acc2[m][2].y;
            v1.z = acc2[m][3].x; v1.w = acc2[m][3].y;
            Sg[q0 * 512       + 4 * rq + m] = v0;
            Sg[(q0 + 1) * 512 + 4 * rq + m] = v1;
        }
    }
    __syncthreads();                      // planes complete

    {   // dgl[t] = a . gl[t], dgr[t] = a . gr[t] (lane-consecutive reads)
        float dl = 0.f, dr = 0.f;
#pragma unroll
        for (int q = 0; q < 4; ++q) {
            const float4 vl = Sgl[q * 512 + t];
            const float4 vr = Sgr[q * 512 + t];
            dl = fmaf(a[4*q+0], vl.x, dl); dl = fmaf(a[4*q+1], vl.y, dl);
            dl = fmaf(a[4*q+2], vl.z, dl); dl = fmaf(a[4*q+3], vl.w, dl);
            dr = fmaf(a[4*q+0], vr.x, dr); dr = fmaf(a[4*q+1], vr.y, dr);
            dr = fmaf(a[4*q+2], vr.z, dr); dr = fmaf(a[4*q+3], vr.w, dr);
        }
        s_dgl[t] = dl;
        s_dgr[t] = dr;
    }
    __syncthreads();                      // dgl/dgr ready -- LAST barrier

    // ================= wave-autonomous attention (recompute, no sc[]) =====
    const int lane = t & 63;
    const int g    = lane >> 3;           // row group within wave
    const int lg   = lane & 7;            // lane within group
    const int row  = i0 + (t >> 6) * 8 + g;

    // row's gr fragment (8 lanes same row -> broadcast reads)
    f32x2 grip[8];
#pragma unroll
    for (int q = 0; q < 4; ++q) {
        const float4 v = Sgr[q * 512 + row];
        grip[2*q+0] = (f32x2){v.x, v.y};
        grip[2*q+1] = (f32x2){v.z, v.w};
    }
    const float cc = 0.6f * s_dgr[row];

    // mask bits for this lane's 64 j (cached: 16 regs)
    uint32_t mb[16];
#pragma unroll
    for (int w = 0; w < 16; ++w) {
        if (lay == 0) {
            const int* arow = adj + ((size_t)(b * NN + row)) * NN + w * 32 + lg;
            uint32_t m  = (arow[0]  != 0 ? 1u : 0u);
            m |= (arow[8]  != 0 ? 2u : 0u);
            m |= (arow[16] != 0 ? 4u : 0u);
            m |= (arow[24] != 0 ? 8u : 0u);
            mb[w] = m;
        } else {
            const uint32_t word = adjb[((size_t)(b * NN + row)) * 16 + w];
            mb[w] = ((word >> lg) & 1u)
                  | (((word >> ( 8 + lg)) & 1u) << 1)
                  | (((word >> (16 + lg)) & 1u) << 2)
                  | (((word >> (24 + lg)) & 1u) << 3);
        }
    }

    // ---- pass 1: row max only (no score storage) ----
    float mx = SENTINEL;
#pragma unroll
    for (int w = 0; w < 16; ++w) {
#pragma unroll
        for (int u = 0; u < 4; ++u) {
            const int j = w * 32 + u * 8 + lg;
            const float dj = s_dgl[j];
            float s = 0.f;
#pragma unroll
            for (int q = 0; q < 4; ++q) {
                const float4 gv = Sgl[q * 512 + j];   // 8 consecutive addrs/wave
                const f32x2 Ga = {gv.x, gv.y}, Gb = {gv.z, gv.w};
                const f32x2 va = pk_add(Ga, grip[2*q+0]);
                const f32x2 vb = pk_add(Gb, grip[2*q+1]);
                s = fmaf(a[4*q+0], fabsf(va.x), s);
                s = fmaf(a[4*q+1], fabsf(va.y), s);
                s = fmaf(a[4*q+2], fabsf(vb.x), s);
                s = fmaf(a[4*q+3], fabsf(vb.y), s);
            }
            const float bb = fmaf(0.6f, dj, cc);
            const float v  = ((mb[w] >> u) & 1u) ? fmaf(0.4f, s, bb) : SENTINEL;
            mx = fmaxf(mx, v);
        }
    }
    // group (= full row) max via butterfly
    mx = fmaxf(mx, __shfl_xor(mx, 1));
    mx = fmaxf(mx, __shfl_xor(mx, 2));
    mx = fmaxf(mx, __shfl_xor(mx, 4));

    // ---- pass 2: recompute score -> exp -> denom + PV accumulate ----
    float L = 0.f;
    f32x2 accp[8];
#pragma unroll
    for (int p2 = 0; p2 < 8; ++p2) accp[p2] = (f32x2){0.f, 0.f};
#pragma unroll
    for (int w = 0; w < 16; ++w) {
#pragma unroll
        for (int u = 0; u < 4; ++u) {
            const int j = w * 32 + u * 8 + lg;
            const float dj = s_dgl[j];
            float s = 0.f;
#pragma unroll
            for (int q = 0; q < 4; ++q) {
                const float4 gv = Sgl[q * 512 + j];
                const f32x2 Ga = {gv.x, gv.y}, Gb = {gv.z, gv.w};
                const f32x2 va = pk_add(Ga, grip[2*q+0]);
                const f32x2 vb = pk_add(Gb, grip[2*q+1]);
                s = fmaf(a[4*q+0], fabsf(va.x), s);
                s = fmaf(a[4*q+1], fabsf(va.y), s);
                s = fmaf(a[4*q+2], fabsf(vb.x), s);
                s = fmaf(a[4*q+3], fabsf(vb.y), s);
            }
            const float bb = fmaf(0.6f, dj, cc);
            const float v  = ((mb[w] >> u) & 1u) ? fmaf(0.4f, s, bb) : SENTINEL;
            const float p  = __expf(v - mx);      // masked -> exp(-huge) = 0
            L += p;
            const f32x2 pp = {p, p};
#pragma unroll
            for (int q = 0; q < 4; ++q) {
                const float4 gv = Sgr[q * 512 + j];
                const f32x2 Ga = {gv.x, gv.y}, Gb = {gv.z, gv.w};
                accp[2*q+0] = pk_fma_blo(Ga, pp, accp[2*q+0]);
                accp[2*q+1] = pk_fma_blo(Gb, pp, accp[2*q+1]);
            }
        }
    }
    L += __shfl_xor(L, 1);
    L += __shfl_xor(L, 2);
    L += __shfl_xor(L, 4);
    const float inv = 1.f / L;

    // butterfly acc merge within group (all 8 lanes end with full row acc)
#pragma unroll
    for (int p2 = 0; p2 < 8; ++p2) accp[p2] = pk_add(accp[p2], shfl_xor_f2(accp[p2], 1));
#pragma unroll
    for (int p2 = 0; p2 < 8; ++p2) accp[p2] = pk_add(accp[p2], shfl_xor_f2(accp[p2], 2));
#pragma unroll
    for (int p2 = 0; p2 < 8; ++p2) accp[p2] = pk_add(accp[p2], shfl_xor_f2(accp[p2], 4));

    // ---- normalize + write (lane lg owns f = 2lg, 2lg+1) ----
    const f32x2 acc_o = accp[lg] * (f32x2){inv, inv};
    if (Wout) {                           // fused h @ W_out per head
        const float w0 = Wout[hh * NHID + 2 * lg];
        const float w1 = Wout[hh * NHID + 2 * lg + 1];
        float v = acc_o.x * w0 + acc_o.y * w1;
        v += __shfl_xor(v, 1);
        v += __shfl_xor(v, 2);
        v += __shfl_xor(v, 4);
        if (lg == 0) atomicAdd(out + b * NN + row, v);
    } else {                              // transposed activation for next layer
        float* dst = hTout + ((size_t)b * DH + hh * NHID + 2 * lg) * NN + row;
        dst[0]  = acc_o.x;
        dst[NN] = acc_o.y;
    }

    // layer 1 zeroes the atomic target for layer 2 (stream-ordered)
    if (lay == 1 && blk < 4) out[blk * 512 + t] = 0.f;
}

extern "C" void kernel_launch(void* const* d_in, const int* in_sizes, int n_in,
                              void* d_out, int out_size, void* d_ws, size_t ws_size,
                              hipStream_t stream) {
    const float* X    = (const float*)d_in[0];   // [4,512,2]
    const int*   adj  = (const int*)  d_in[1];   // [4,512,512]
    const float* Win  = (const float*)d_in[2];   // [2,128]
    const float* Wl   = (const float*)d_in[3];   // [3,128,128]
    const float* Wr   = (const float*)d_in[4];   // [3,128,128]
    const float* Aa   = (const float*)d_in[5];   // [3,16]
    const float* Wout = (const float*)d_in[6];   // [128,1]
    float* out = (float*)d_out;                  // [4,512] fp32

    float*    ws   = (float*)d_ws;
    float*    hT_a = ws;                         // 1 MB, [4][128][512]
    float*    hT_b = ws + 262144;                // 1 MB
    uint32_t* adjb = (uint32_t*)(ws + 524288);   // 128 KB

    gat_layer<<<256, 512, 0, stream>>>(0, X, nullptr, hT_a, Win,
        Wl,               Wr,               Aa,      nullptr, out, adjb, adj);
    gat_layer<<<256, 512, 0, stream>>>(1, nullptr, hT_a, hT_b, Win,
        Wl + DH * DH,     Wr + DH * DH,     Aa + 16, nullptr, out, adjb, adj);
    gat_layer<<<256, 512, 0, stream>>>(2, nullptr, hT_b, nullptr, Win,
        Wl + 2 * DH * DH, Wr + 2 * DH * DH, Aa + 32, Wout,    out, adjb, adj);
}

// Round 16
// 161.177 us; speedup vs baseline: 6.5427x; 1.0611x over previous
//
#include <hip/hip_runtime.h>
#include <cstdint>
#include <math.h>

#define NB 4
#define NN 512
#define DH 128
#define NHEADS 8
#define NHID 16
#define ITILE 64
#define SENTINEL -1e30f

// ---- packed-f32 helpers (VOP3P, gfx90a+): 2 IEEE f32 ops per instr ----
typedef __attribute__((ext_vector_type(2))) float f32x2;

// d = a*b + c (both halves), b.lo broadcast to both halves
__device__ __forceinline__ f32x2 pk_fma_blo(f32x2 a, f32x2 b, f32x2 c) {
    f32x2 d;
    asm("v_pk_fma_f32 %0, %1, %2, %3 op_sel_hi:[1,0,1]"
        : "=v"(d) : "v"(a), "v"(b), "v"(c));
    return d;
}
// d = a*b + c (both halves), b.hi broadcast to both halves
__device__ __forceinline__ f32x2 pk_fma_bhi(f32x2 a, f32x2 b, f32x2 c) {
    f32x2 d;
    asm("v_pk_fma_f32 %0, %1, %2, %3 op_sel:[0,1,0] op_sel_hi:[1,1,1]"
        : "=v"(d) : "v"(a), "v"(b), "v"(c));
    return d;
}
__device__ __forceinline__ f32x2 pk_add(f32x2 a, f32x2 b) {
    f32x2 d;
    asm("v_pk_add_f32 %0, %1, %2" : "=v"(d) : "v"(a), "v"(b));
    return d;
}

// ---- fully-fused GAT layer (R9-verified best, 155.0 us) ----
// 3 dispatches total. Block (b, hh, it): 512 threads, 95.9 KB LDS, 1 block/CU.
// Session ledger (15 rounds): this structure beat every alternative tested
// on silicon -- 6-dispatch split (+11us), cooperative fusion (+800us),
// scalar-pipe W (+52us), 2x8 swp pipeline (compiler sank regs), 1024-thread
// attn (heavier merge), barrier-free wave-autonomous attn (+5us after
// spill-proofing; refuted the barrier-drain theory -- the kernel sits at
// the joint LDS-return-path + VALU floor for this algorithm shape).
// Wins banked here: 2-row LDS amortization (R2), 3-dispatch fusion (R4),
// 16-deep load batching (R8), packed v_pk_fma_f32/v_pk_add_f32 (R9).
// proj: thread (c4,rq) -> rows 4rq..4rq+3 x 8 cols; hT loads batched
// 16-deep; W octets via LDS broadcast. Score: factored lrelu
// e = 0.6*(dgl[j]+dgr[i]) + 0.4*sum a_f|gl+gr|. Two-pass register softmax.
// Layer 0 packs adj bitmasks; layer 1 zeroes out[]; layer 2 fuses @W_out.
__global__ __launch_bounds__(512, 1) void gat_layer(
    const int lay,
    const float* __restrict__ X,
    const float* __restrict__ hTin, float* __restrict__ hTout,
    const float* __restrict__ Win,
    const float* __restrict__ WlL, const float* __restrict__ WrL,
    const float* __restrict__ a_vec, const float* __restrict__ Wout,
    float* __restrict__ out, uint32_t* __restrict__ adjb,
    const int* __restrict__ adj)
{
    __shared__ __align__(16) float smem[23968];   // 95,872 B -> 1 block/CU
    float* s_W   = smem;                  // [128][32] cols 0-15 Wl, 16-31 Wr
    float* s_Win = smem + 4096;           // [2][128] (layer 0 only)
    float4* Sgl  = (float4*)(smem + 4352);   // [4][512] f-major gl chunks
    float4* Sgr  = (float4*)(smem + 12544);  // [4][512] f-major gr chunks
    float* s_dgl = smem + 20736;          // [512]
    float* s_dgr = smem + 21248;          // [512]
    float* s_m   = smem + 21760;          // [16][65]
    float* s_l   = smem + 22800;          // [16][65]
    float* s_M   = smem + 23840;          // [64]
    float* s_inv = smem + 23904;          // [64]
    float* s_acc = smem;                  // alias [16][64][16], dead post-PV

    const int blk = blockIdx.x;           // 256 = ((b*8+hh)*8) + it
    const int it  = blk & 7;
    const int bh  = blk >> 3;
    const int b   = bh >> 3;
    const int hh  = bh & 7;
    const int i0  = it * ITILE;
    const int t   = threadIdx.x;
    const int il  = t & 31;
    const int js  = t >> 5;               // [0,16)
    const int r0  = i0 + il;
    const int r1  = r0 + 32;

    // ---- stage W head-slices -> s_W[k][32]; Win (layer 0) ----
    for (int c = t; c < 1024; c += 512) {
        const int k = c >> 3, j = c & 7;
        if (j < 4)
            *(float4*)&s_W[k * 32 + j * 4] =
                *(const float4*)&WlL[k * DH + hh * NHID + j * 4];
        else
            *(float4*)&s_W[k * 32 + 16 + (j - 4) * 4] =
                *(const float4*)&WrL[k * DH + hh * NHID + (j - 4) * 4];
    }
    if (lay == 0 && t < 64) ((float4*)s_Win)[t] = ((const float4*)Win)[t];

    float a[16];
#pragma unroll
    for (int q = 0; q < 4; ++q) {
        const float4 v = ((const float4*)a_vec)[q];
        a[4*q+0] = v.x; a[4*q+1] = v.y; a[4*q+2] = v.z; a[4*q+3] = v.w;
    }

    // ---- masks: layer 0 packs from adj (and stores for reuse); else load ----
    uint32_t mask0, mask1;
    if (lay == 0) {
        const int4* p0 = (const int4*)(adj + ((size_t)(b * NN + r0)) * NN + js * 32);
        const int4* p1 = (const int4*)(adj + ((size_t)(b * NN + r1)) * NN + js * 32);
        uint32_t m0 = 0, m1 = 0;
#pragma unroll
        for (int c = 0; c < 8; ++c) {
            const int4 v0 = p0[c], v1 = p1[c];
            m0 |= (v0.x != 0 ? 1u : 0u) << (c * 4 + 0);
            m0 |= (v0.y != 0 ? 1u : 0u) << (c * 4 + 1);
            m0 |= (v0.z != 0 ? 1u : 0u) << (c * 4 + 2);
            m0 |= (v0.w != 0 ? 1u : 0u) << (c * 4 + 3);
            m1 |= (v1.x != 0 ? 1u : 0u) << (c * 4 + 0);
            m1 |= (v1.y != 0 ? 1u : 0u) << (c * 4 + 1);
            m1 |= (v1.z != 0 ? 1u : 0u) << (c * 4 + 2);
            m1 |= (v1.w != 0 ? 1u : 0u) << (c * 4 + 3);
        }
        mask0 = m0; mask1 = m1;
        adjb[((size_t)(b * NN + r0)) * 16 + js] = m0;  // 8 hh-blocks same value: benign
        adjb[((size_t)(b * NN + r1)) * 16 + js] = m1;
    } else {
        mask0 = adjb[((size_t)(b * NN + r0)) * 16 + js];
        mask1 = adjb[((size_t)(b * NN + r1)) * 16 + js];
    }
    __syncthreads();                      // s_W/s_Win staged

    // ---- proj: thread (c4, rq) -> rows 4rq..4rq+3, cols c4*8..+7 ----
    {
        const int c4 = t >> 7;            // wave-uniform (2 waves per c4)
        const int rq = t & 127;
        const float* wcol = s_W + ((c4 >> 1) * 16 + (c4 & 1) * 8);
        f32x2 acc2[4][4];                 // [row][colpair]
#pragma unroll
        for (int m = 0; m < 4; ++m)
#pragma unroll
            for (int c = 0; c < 4; ++c) acc2[m][c] = (f32x2){0.f, 0.f};

        if (lay == 0) {
            const float4 xa = *(const float4*)&X[(size_t)(b * NN + 4 * rq) * 2];
            const float4 xb = *(const float4*)&X[(size_t)(b * NN + 4 * rq) * 2 + 4];
            const float x0[4] = {xa.x, xa.z, xb.x, xb.z};
            const float x1[4] = {xa.y, xa.w, xb.y, xb.w};
#pragma unroll 2
            for (int kq = 0; kq < 32; ++kq) {
                const float4 w0 = *(const float4*)&s_Win[kq * 4];
                const float4 w1 = *(const float4*)&s_Win[128 + kq * 4];
                const float w0a[4] = {w0.x, w0.y, w0.z, w0.w};
                const float w1a[4] = {w1.x, w1.y, w1.z, w1.w};
#pragma unroll
                for (int kk = 0; kk < 4; ++kk) {
                    const int k = kq * 4 + kk;
                    const float4 wa = *(const float4*)&wcol[k * 32];
                    const float4 wb = *(const float4*)&wcol[k * 32 + 4];
                    const f32x2 W0 = {wa.x, wa.y}, W1 = {wa.z, wa.w};
                    const f32x2 W2 = {wb.x, wb.y}, W3 = {wb.z, wb.w};
                    const float hm0 = x0[0] * w0a[kk] + x1[0] * w1a[kk];
                    const float hm1 = x0[1] * w0a[kk] + x1[1] * w1a[kk];
                    const float hm2 = x0[2] * w0a[kk] + x1[2] * w1a[kk];
                    const float hm3 = x0[3] * w0a[kk] + x1[3] * w1a[kk];
                    const f32x2 H0 = {hm0, hm1}, H1 = {hm2, hm3};
                    acc2[0][0] = pk_fma_blo(W0, H0, acc2[0][0]);
                    acc2[0][1] = pk_fma_blo(W1, H0, acc2[0][1]);
                    acc2[0][2] = pk_fma_blo(W2, H0, acc2[0][2]);
                    acc2[0][3] = pk_fma_blo(W3, H0, acc2[0][3]);
                    acc2[1][0] = pk_fma_bhi(W0, H0, acc2[1][0]);
                    acc2[1][1] = pk_fma_bhi(W1, H0, acc2[1][1]);
                    acc2[1][2] = pk_fma_bhi(W2, H0, acc2[1][2]);
                    acc2[1][3] = pk_fma_bhi(W3, H0, acc2[1][3]);
                    acc2[2][0] = pk_fma_blo(W0, H1, acc2[2][0]);
                    acc2[2][1] = pk_fma_blo(W1, H1, acc2[2][1]);
                    acc2[2][2] = pk_fma_blo(W2, H1, acc2[2][2]);
                    acc2[2][3] = pk_fma_blo(W3, H1, acc2[2][3]);
                    acc2[3][0] = pk_fma_bhi(W0, H1, acc2[3][0]);
                    acc2[3][1] = pk_fma_bhi(W1, H1, acc2[3][1]);
                    acc2[3][2] = pk_fma_bhi(W2, H1, acc2[3][2]);
                    acc2[3][3] = pk_fma_bhi(W3, H1, acc2[3][3]);
                }
            }
        } else {
            const float* hT = hTin + (size_t)b * DH * NN + 4 * rq;   // [128][512]
#pragma unroll 1
            for (int kb = 0; kb < DH; kb += 16) {
                float4 hb[16];            // 16 independent loads in flight
#pragma unroll
                for (int u = 0; u < 16; ++u)
                    hb[u] = *(const float4*)&hT[(size_t)(kb + u) * NN];
#pragma unroll
                for (int u = 0; u < 16; ++u) {
                    const int k = kb + u;
                    const float4 wa = *(const float4*)&wcol[k * 32];  // broadcast
                    const float4 wb = *(const float4*)&wcol[k * 32 + 4];
                    const f32x2 W0 = {wa.x, wa.y}, W1 = {wa.z, wa.w};
                    const f32x2 W2 = {wb.x, wb.y}, W3 = {wb.z, wb.w};
                    const f32x2 H0 = {hb[u].x, hb[u].y}, H1 = {hb[u].z, hb[u].w};
                    acc2[0][0] = pk_fma_blo(W0, H0, acc2[0][0]);
                    acc2[0][1] = pk_fma_blo(W1, H0, acc2[0][1]);
                    acc2[0][2] = pk_fma_blo(W2, H0, acc2[0][2]);
                    acc2[0][3] = pk_fma_blo(W3, H0, acc2[0][3]);
                    acc2[1][0] = pk_fma_bhi(W0, H0, acc2[1][0]);
                    acc2[1][1] = pk_fma_bhi(W1, H0, acc2[1][1]);
                    acc2[1][2] = pk_fma_bhi(W2, H0, acc2[1][2]);
                    acc2[1][3] = pk_fma_bhi(W3, H0, acc2[1][3]);
                    acc2[2][0] = pk_fma_blo(W0, H1, acc2[2][0]);
                    acc2[2][1] = pk_fma_blo(W1, H1, acc2[2][1]);
                    acc2[2][2] = pk_fma_blo(W2, H1, acc2[2][2]);
                    acc2[2][3] = pk_fma_blo(W3, H1, acc2[2][3]);
                    acc2[3][0] = pk_fma_bhi(W0, H1, acc2[3][0]);
                    acc2[3][1] = pk_fma_bhi(W1, H1, acc2[3][1]);
                    acc2[3][2] = pk_fma_bhi(W2, H1, acc2[3][2]);
                    acc2[3][3] = pk_fma_bhi(W3, H1, acc2[3][3]);
                }
            }
        }
        // write f-major plane slices
        float4* Sg = (c4 < 2) ? Sgl : Sgr;
        const int q0 = (c4 & 1) * 2;
#pragma unroll
        for (int m = 0; m < 4; ++m) {
            float4 v0, v1;
            v0.x = acc2[m][0].x; v0.y = acc2[m][0].y;
            v0.z = acc2[m][1].x; v0.w = acc2[m][1].y;
            v1.x = acc2[m][2].x; v1.y = acc2[m][2].y;
            v1.z = acc2[m][3].x; v1.w = acc2[m][3].y;
            Sg[q0 * 512       + 4 * rq + m] = v0;
            Sg[(q0 + 1) * 512 + 4 * rq + m] = v1;
        }
    }
    __syncthreads();                      // planes complete

    {   // dgl[t] = a . gl[t], dgr[t] = a . gr[t] (lane-consecutive reads)
        float dl = 0.f, dr = 0.f;
#pragma unroll
        for (int q = 0; q < 4; ++q) {
            const float4 vl = Sgl[q * 512 + t];
            const float4 vr = Sgr[q * 512 + t];
            dl = fmaf(a[4*q+0], vl.x, dl); dl = fmaf(a[4*q+1], vl.y, dl);
            dl = fmaf(a[4*q+2], vl.z, dl); dl = fmaf(a[4*q+3], vl.w, dl);
            dr = fmaf(a[4*q+0], vr.x, dr); dr = fmaf(a[4*q+1], vr.y, dr);
            dr = fmaf(a[4*q+2], vr.z, dr); dr = fmaf(a[4*q+3], vr.w, dr);
        }
        s_dgl[t] = dl;
        s_dgr[t] = dr;
    }
    __syncthreads();                      // dgl/dgr ready

    // ---- gri for own 2 rows (as f32x2 pairs) ----
    f32x2 gri0p[8], gri1p[8];
#pragma unroll
    for (int q = 0; q < 4; ++q) {
        const float4 v0 = Sgr[q * 512 + r0];
        const float4 v1 = Sgr[q * 512 + r1];
        gri0p[2*q+0] = (f32x2){v0.x, v0.y}; gri0p[2*q+1] = (f32x2){v0.z, v0.w};
        gri1p[2*q+0] = (f32x2){v1.x, v1.y}; gri1p[2*q+1] = (f32x2){v1.z, v1.w};
    }

    // ---- pass 1: scores for 2 rows x 32 j (pk_add + scalar |.| fma) ----
    const float c0 = 0.6f * s_dgr[r0];
    const float c1 = 0.6f * s_dgr[r1];
    const int jbase = js * 32;
    float sc0[32], sc1[32];
#pragma unroll
    for (int jj = 0; jj < 32; ++jj) {
        const int j = jbase + jj;
        const float dj = s_dgl[j];
        float s0 = 0.f, s1 = 0.f;
#pragma unroll
        for (int q = 0; q < 4; ++q) {
            const float4 g = Sgl[q * 512 + j];   // uniform j -> broadcast
            const f32x2 Ga = {g.x, g.y}, Gb = {g.z, g.w};
            const f32x2 v0a = pk_add(Ga, gri0p[2*q+0]);
            const f32x2 v0b = pk_add(Gb, gri0p[2*q+1]);
            const f32x2 v1a = pk_add(Ga, gri1p[2*q+0]);
            const f32x2 v1b = pk_add(Gb, gri1p[2*q+1]);
            s0 = fmaf(a[4*q+0], fabsf(v0a.x), s0);
            s0 = fmaf(a[4*q+1], fabsf(v0a.y), s0);
            s0 = fmaf(a[4*q+2], fabsf(v0b.x), s0);
            s0 = fmaf(a[4*q+3], fabsf(v0b.y), s0);
            s1 = fmaf(a[4*q+0], fabsf(v1a.x), s1);
            s1 = fmaf(a[4*q+1], fabsf(v1a.y), s1);
            s1 = fmaf(a[4*q+2], fabsf(v1b.x), s1);
            s1 = fmaf(a[4*q+3], fabsf(v1b.y), s1);
        }
        const float b0 = fmaf(0.6f, dj, c0);
        const float b1 = fmaf(0.6f, dj, c1);
        sc0[jj] = ((mask0 >> jj) & 1u) ? fmaf(0.4f, s0, b0) : SENTINEL;
        sc1[jj] = ((mask1 >> jj) & 1u) ? fmaf(0.4f, s1, b1) : SENTINEL;
    }

    // ---- in-register softmax (two-pass) ----
    float m0 = sc0[0], m1 = sc1[0];
#pragma unroll
    for (int jj = 1; jj < 32; ++jj) { m0 = fmaxf(m0, sc0[jj]); m1 = fmaxf(m1, sc1[jj]); }
    float l0 = 0.f, l1 = 0.f;
#pragma unroll
    for (int jj = 0; jj < 32; ++jj) {
        sc0[jj] = __expf(sc0[jj] - m0); l0 += sc0[jj];
        sc1[jj] = __expf(sc1[jj] - m1); l1 += sc1[jj];
    }
    s_m[js * 65 + il]      = m0;
    s_m[js * 65 + il + 32] = m1;
    s_l[js * 65 + il]      = l0;
    s_l[js * 65 + il + 32] = l1;

    // ---- pass 2: PV aggregation (packed, {p0,p1} op_sel broadcast) ----
    f32x2 acc0p[8], acc1p[8];
#pragma unroll
    for (int f = 0; f < 8; ++f) { acc0p[f] = (f32x2){0.f, 0.f}; acc1p[f] = (f32x2){0.f, 0.f}; }
#pragma unroll
    for (int jj = 0; jj < 32; ++jj) {
        const int j = jbase + jj;
        const f32x2 pp = {sc0[jj], sc1[jj]};
#pragma unroll
        for (int q = 0; q < 4; ++q) {
            const float4 g = Sgr[q * 512 + j];   // broadcast
            const f32x2 Ga = {g.x, g.y}, Gb = {g.z, g.w};
            acc0p[2*q+0] = pk_fma_blo(Ga, pp, acc0p[2*q+0]);
            acc0p[2*q+1] = pk_fma_blo(Gb, pp, acc0p[2*q+1]);
            acc1p[2*q+0] = pk_fma_bhi(Ga, pp, acc1p[2*q+0]);
            acc1p[2*q+1] = pk_fma_bhi(Gb, pp, acc1p[2*q+1]);
        }
    }
    __syncthreads();                      // retires plane reads + s_m/s_l writes

    if (t < 64) {                         // per-row global max + denom over 16 slices
        float M = SENTINEL;
#pragma unroll
        for (int k = 0; k < 16; ++k) M = fmaxf(M, s_m[k * 65 + t]);
        float L = 0.f;
#pragma unroll
        for (int k = 0; k < 16; ++k) L += s_l[k * 65 + t] * __expf(s_m[k * 65 + t] - M);
        s_M[t]   = M;
        s_inv[t] = 1.f / L;
    }
    __syncthreads();

    {   // scaled partials into aliased scratch; chunk-XOR swizzle
        const float k0 = __expf(m0 - s_M[il])      * s_inv[il];
        const float k1 = __expf(m1 - s_M[il + 32]) * s_inv[il + 32];
        const int swz = il & 3;
        float* base_a = s_acc + js * 1024;
#pragma unroll
        for (int q = 0; q < 4; ++q) {
            float4 v0, v1;
            v0.x = acc0p[2*q+0].x * k0; v0.y = acc0p[2*q+0].y * k0;
            v0.z = acc0p[2*q+1].x * k0; v0.w = acc0p[2*q+1].y * k0;
            v1.x = acc1p[2*q+0].x * k1; v1.y = acc1p[2*q+0].y * k1;
            v1.z = acc1p[2*q+1].x * k1; v1.w = acc1p[2*q+1].y * k1;
            *(float4*)(base_a + il * 16        + 4 * (q ^ swz)) = v0;
            *(float4*)(base_a + (il + 32) * 16 + 4 * (q ^ swz)) = v1;
        }
    }
    __syncthreads();

    {   // final reduce over 16 slices: thread (i = t>>4, f = t&15), 2 rows each
        const int i  = t >> 4;
        const int f  = t & 15;
        const int e  = f & 3, qf = f >> 2;
#pragma unroll
        for (int r = 0; r < 2; ++r) {
            const int lr = i + r * 32;
            const int w  = lr * 16 + 4 * (qf ^ (lr & 3)) + e;
            float o = 0.f;
#pragma unroll
            for (int k = 0; k < 16; ++k) o += s_acc[k * 1024 + w];
            const int grow = i0 + lr;
            if (Wout) {                   // fused h @ W_out partial per head
                float v = o * Wout[hh * NHID + f];
#pragma unroll
                for (int off = 8; off; off >>= 1) v += __shfl_xor(v, off);
                if (f == 0) atomicAdd(out + b * NN + grow, v);
            } else {                      // transposed activation for next layer
                hTout[((size_t)b * DH + hh * NHID + f) * NN + grow] = o;
            }
        }
    }

    // layer 1 zeroes the atomic target for layer 2 (stream-ordered)
    if (lay == 1 && blk < 4) out[blk * 512 + t] = 0.f;
}

extern "C" void kernel_launch(void* const* d_in, const int* in_sizes, int n_in,
                              void* d_out, int out_size, void* d_ws, size_t ws_size,
                              hipStream_t stream) {
    const float* X    = (const float*)d_in[0];   // [4,512,2]
    const int*   adj  = (const int*)  d_in[1];   // [4,512,512]
    const float* Win  = (const float*)d_in[2];   // [2,128]
    const float* Wl   = (const float*)d_in[3];   // [3,128,128]
    const float* Wr   = (const float*)d_in[4];   // [3,128,128]
    const float* Aa   = (const float*)d_in[5];   // [3,16]
    const float* Wout = (const float*)d_in[6];   // [128,1]
    float* out = (float*)d_out;                  // [4,512] fp32

    float*    ws   = (float*)d_ws;
    float*    hT_a = ws;                         // 1 MB, [4][128][512]
    float*    hT_b = ws + 262144;                // 1 MB
    uint32_t* adjb = (uint32_t*)(ws + 524288);   // 128 KB

    gat_layer<<<256, 512, 0, stream>>>(0, X, nullptr, hT_a, Win,
        Wl,               Wr,               Aa,      nullptr, out, adjb, adj);
    gat_layer<<<256, 512, 0, stream>>>(1, nullptr, hT_a, hT_b, Win,
        Wl + DH * DH,     Wr + DH * DH,     Aa + 16, nullptr, out, adjb, adj);
    gat_layer<<<256, 512, 0, stream>>>(2, nullptr, hT_b, nullptr, Win,
        Wl + 2 * DH * DH, Wr + 2 * DH * DH, Aa + 32, Wout,    out, adjb, adj);
}